// Round 9
// baseline (190.162 us; speedup 1.0000x reference)
//
#include <hip/hip_runtime.h>
#include <stdint.h>

// Bit-serial conv2d closed form: term = sign(w) * ((x * |w|) >> 4)
//                                     = (x * w + A) >> 4   [arith shift, per i16 lane]
// where A = (w<0) ? 15 : 0.  x in [0,15], w in [-8,7].
// out = relu(bias + sum_{3x3,c} term).  B=4 H=32 W=32 C=64 F=128.
//
// ROUND 9 = INSTRUMENTATION ROUND.  conv_main replicated x8 via grid
// (bid = blockIdx.x & 2047; the 8 replicas write identical values -> output
// unchanged).  Purpose: the replicated dispatch (~8x conv) becomes the top
// rocprof dispatch, exposing VALUBusy / FETCH_SIZE / LDS conflicts /
// Occupancy for conv itself, and dur/8 gives the true marginal cost.

#define XOFF 36864            // dword offset of padded x in ws
#define NXPK 147968           // 4*34*34*32 padded input dwords (2 i16 each)

static __device__ __forceinline__ int pk_mad_i16(int a, int b, int c) {
    int d;
    asm("v_pk_mad_i16 %0, %1, %2, %3" : "=v"(d) : "v"(a), "v"(b), "v"(c));
    return d;
}
static __device__ __forceinline__ int pk_ashr(int sh, int a) {
    int d;
    asm("v_pk_ashrrev_i16 %0, %1, %2" : "=v"(d) : "v"(sh), "v"(a));
    return d;
}
static __device__ __forceinline__ int pk_add_i16(int a, int b) {
    int d;
    asm("v_pk_add_i16 %0, %1, %2" : "=v"(d) : "v"(a), "v"(b));
    return d;
}

// blocks [0,144): weight pack; [144,723): pad+pack x.
// Weight dword index: ((ki*2+fh)*512 + ce*64 + f64)*4 + u
__global__ __launch_bounds__(256) void prep_all(const float* __restrict__ kern,
                                                const float* __restrict__ input,
                                                uint32_t* __restrict__ ws) {
    int bid = blockIdx.x, tid = threadIdx.x;
    if (bid < 144) {
        int t    = bid * 256 + tid;          // < 36864
        int u    = t & 3;
        int rest = t >> 2;
        int f64  = rest & 63;
        int ce   = (rest >> 6) & 7;
        int kifh = rest >> 9;                // ki*2 + fh
        int fh   = kifh & 1;
        int ki   = kifh >> 1;
        int c    = ce * 8 + u * 2;
        int f    = fh * 64 + f64;
        int wlo = (int)kern[(ki * 64 + c    ) * 128 + f];   // src [ki][c][f]
        int whi = (int)kern[(ki * 64 + c + 1) * 128 + f];
        ws[t] = (uint32_t)(uint16_t)(int16_t)wlo |
                ((uint32_t)(uint16_t)(int16_t)whi << 16);
    } else {
        int t = (bid - 144) * 256 + tid;     // < 147968
        if (t >= NXPK) return;
        int c2    = t & 31;
        int rest  = t >> 5;                  // b*34*34 + hp*34 + wp
        int wp    = rest % 34;
        int rest2 = rest / 34;
        int hp    = rest2 % 34;
        int b     = rest2 / 34;
        int v = 0;
        if (hp >= 1 && hp <= 32 && wp >= 1 && wp <= 32) {
            const float* p = &input[(((b * 32) + hp - 1) * 32 + (wp - 1)) * 64 + c2 * 2];
            v = (int)p[0] | ((int)p[1] << 16);
        }
        ws[XOFF + t] = (uint32_t)v;
    }
}

// 16384 blocks x 512 threads = 8 replicas of the 2048-block R8 kernel.
// Block = (b, h, wq, fh): 4 output cols x 64 f.
__global__ __launch_bounds__(512, 4) void conv_main(const uint32_t* __restrict__ ws,
                                                    const float* __restrict__ bias,
                                                    float* __restrict__ out) {
    const uint32_t* xpk = ws + XOFF;

    int bid = blockIdx.x & 2047;   // 8 replicas do identical work
    int fh  = bid & 1;
    int wq  = (bid >> 1) & 7;
    int h   = (bid >> 4) & 31;
    int b   = bid >> 9;
    int tid = threadIdx.x;
    int f64 = tid & 63;
    int ce  = tid >> 6;            // wave-uniform
    int w0  = wq * 4;

    __shared__ uint32_t xl[3 * 6 * 32];    // [row][col 0..5][c2]   2.25 KB
    __shared__ int prt[8 * 4 * 64];        // partial [ce][px][f64] 8 KB

    // stage x-patch: 576 dwords (pre-padded global -> no bounds checks)
    #pragma unroll
    for (int pass = 0; pass < 2; ++pass) {
        int k = pass * 512 + tid;
        if (k < 576) {
            int c2  = k & 31;
            int rc  = k >> 5;
            int col = rc % 6;
            int r   = rc / 6;
            xl[k] = xpk[((b * 34 + h + r) * 34 + (w0 + col)) * 32 + c2];
        }
    }

    // weight slice -> 36 VGPRs, one coalesced pass
    int4 wv[9];
    const int4* wp4 = (const int4*)ws;
    #pragma unroll
    for (int ki = 0; ki < 9; ++ki) wv[ki] = wp4[(ki * 2 + fh) * 512 + tid];

    __syncthreads();

    const int SH4  = 0x00040004;   // per-lane shift 4  (VGPR operand)
    const int SH15 = 0x000F000F;   // per-lane shift 15
    int acc0 = 0, acc1 = 0, acc2 = 0, acc3 = 0;   // packed 2x i16

    #pragma unroll
    for (int row = 0; row < 3; ++row) {
        const uint32_t* xb = xl + (row * 6) * 32 + ce * 4;
        int4 xc[6];
        #pragma unroll
        for (int cidx = 0; cidx < 6; ++cidx)
            xc[cidx] = *(const int4*)(xb + cidx * 32);   // ds_read_b128 bcast
        #pragma unroll
        for (int j = 0; j < 3; ++j) {
            const int4 w4 = wv[row * 3 + j];
            #pragma unroll
            for (int u = 0; u < 4; ++u) {
                int w2 = (&w4.x)[u];
                int A  = pk_ashr(SH15, w2) & 0x000F000F;  // 15 per negative lane
                acc0 = pk_add_i16(acc0, pk_ashr(SH4, pk_mad_i16((&xc[j + 0].x)[u], w2, A)));
                acc1 = pk_add_i16(acc1, pk_ashr(SH4, pk_mad_i16((&xc[j + 1].x)[u], w2, A)));
                acc2 = pk_add_i16(acc2, pk_ashr(SH4, pk_mad_i16((&xc[j + 2].x)[u], w2, A)));
                acc3 = pk_add_i16(acc3, pk_ashr(SH4, pk_mad_i16((&xc[j + 3].x)[u], w2, A)));
            }
        }
    }

    // per-thread horizontal add (2 channel halves), stash partial
    prt[(ce * 4 + 0) * 64 + f64] = (int)(short)(acc0 & 0xffff) + (acc0 >> 16);
    prt[(ce * 4 + 1) * 64 + f64] = (int)(short)(acc1 & 0xffff) + (acc1 >> 16);
    prt[(ce * 4 + 2) * 64 + f64] = (int)(short)(acc2 & 0xffff) + (acc2 >> 16);
    prt[(ce * 4 + 3) * 64 + f64] = (int)(short)(acc3 & 0xffff) + (acc3 >> 16);
    __syncthreads();

    // reduce 8 c-eighths, bias, relu, store: 256 outputs, threads [0,256)
    if (tid < 256) {
        int ff = tid & 63;
        int px = tid >> 6;
        int v = 0;
        #pragma unroll
        for (int e = 0; e < 8; ++e) v += prt[(e * 4 + px) * 64 + ff];
        v += (int)bias[fh * 64 + ff];
        out[((b * 32 + h) * 32 + w0 + px) * 128 + fh * 64 + ff] =
            (float)(v < 0 ? 0 : v);
    }
}

extern "C" void kernel_launch(void* const* d_in, const int* in_sizes, int n_in,
                              void* d_out, int out_size, void* d_ws, size_t ws_size,
                              hipStream_t stream) {
    const float* input  = (const float*)d_in[0];   // [4,32,32,64]
    const float* kernel = (const float*)d_in[1];   // [3,3,64,128]
    const float* bias   = (const float*)d_in[2];   // [128]
    // d_in[3] = bits (==4, baked into the closed form)

    uint32_t* ws = (uint32_t*)d_ws;                // 36864 + 147968 dwords used

    prep_all<<<144 + 579, 256, 0, stream>>>(kernel, input, ws);
    conv_main<<<16384, 512, 0, stream>>>(ws, bias, (float*)d_out);   // x8 replicas
}

// Round 10
// 83.568 us; speedup vs baseline: 2.2755x; 2.2755x over previous
//
#include <hip/hip_runtime.h>
#include <stdint.h>

// Bit-serial conv2d closed form: term = sign(w) * ((x * |w|) >> 4)
//                                     = (x * w + A) >> 4   [arith shift, per i16 lane]
// where A = (w<0) ? 15 : 0.  x in [0,15], w in [-8,7].
// out = relu(bias + sum_{3x3,c} term).  B=4 H=32 W=32 C=64 F=128.
//
// Round 10: single fused kernel (no prep, no ws).  R9 instrumentation showed
// conv is VALU-issue-bound (VALUBusy 84%, FETCH 1.2MB, conflicts 0) with
// ~1190 instr/wave vs ~560 core -> strip overhead: inline weight load+cvt
// (L2-hot, imm-offset coalesced), shift-only staging addressing, and
// v_dot2_i32_i16 tied-operand accumulate (kills pk_add chain movs + epilogue
// unpack).

static __device__ __forceinline__ int pk_mad_i16(int a, int b, int c) {
    int d;
    asm("v_pk_mad_i16 %0, %1, %2, %3" : "=v"(d) : "v"(a), "v"(b), "v"(c));
    return d;
}
// per-lane shift amounts MUST be in a VGPR (VOP3P inline consts only splat
// the low 16 bits into the high lane)
static __device__ __forceinline__ int pk_ashr(int sh, int a) {
    int d;
    asm("v_pk_ashrrev_i16 %0, %1, %2" : "=v"(d) : "v"(sh), "v"(a));
    return d;
}
// acc += t.lo16 + t.hi16  (tied dest: no copy on the accumulate chain)
static __device__ __forceinline__ void dot2_acc(int& acc, int t, int ones) {
    asm("v_dot2_i32_i16 %0, %1, %2, %0" : "+v"(acc) : "v"(t), "v"(ones));
}

// 2048 blocks x 512 threads. Block = (b, h, wq, fh): 4 output cols x 64 f.
// Thread (ce = tid>>6 [wave-uniform], f64 = tid&63): 8-ch x 9-pos weight
// slice loaded from raw kernel floats into 9 int4 VGPRs; 6 x-columns per row
// hoisted from LDS; 4 px i32 partials; LDS reduce.
__global__ __launch_bounds__(512, 4) void conv_fused(const float* __restrict__ input,
                                                     const float* __restrict__ kern,
                                                     const float* __restrict__ bias,
                                                     float* __restrict__ out) {
    int bid = blockIdx.x;
    int fh  = bid & 1;
    int wq  = (bid >> 1) & 7;
    int h   = (bid >> 4) & 31;
    int b   = bid >> 9;
    int tid = threadIdx.x;
    int f64 = tid & 63;
    int ce  = tid >> 6;          // wave-uniform
    int w0  = wq * 4;

    __shared__ uint32_t xl[3 * 8 * 32];    // [row][col 0..7][c2]  3 KB (col padded to 8)
    __shared__ int prt[8 * 4 * 64];        // partial [ce][px][f64] 8 KB

    // ---- stage x-patch: 768 entries, shift-only addressing, bounds-checked
    #pragma unroll
    for (int pass = 0; pass < 2; ++pass) {
        int k = pass * 512 + tid;
        if (pass == 0 || k < 768) {
            int c2  = k & 31;
            int col = (k >> 5) & 7;
            int r   = k >> 8;
            int gh  = h + r - 1;
            int gw  = w0 + col - 1;
            uint32_t v = 0;
            if ((unsigned)gh < 32u && (unsigned)gw < 32u && col < 6) {
                const float* p = &input[(((b * 32) + gh) * 32 + gw) * 64 + c2 * 2];
                v = (uint32_t)((int)p[0] | ((int)p[1] << 16));
            }
            xl[k] = v;
        }
    }

    // ---- weight slice: 72 raw floats -> 9 int4 of packed 2xi16
    // addresses: one per-thread base + 9 ki-pointers; within ki all 8 loads
    // use byte imm offsets (c'*512 <= 3584 < 4096) and are lane-coalesced.
    int4 wv[9];
    {
        const float* kp = kern + ce * 1024 + fh * 64 + f64;   // (ce*8)*128 + f
        #pragma unroll
        for (int ki = 0; ki < 9; ++ki) {
            const float* kpi = kp + ki * 8192;                // ki*64*128
            #pragma unroll
            for (int u = 0; u < 4; ++u) {
                int lo = (int)kpi[(u * 2    ) * 128];
                int hi = (int)kpi[(u * 2 + 1) * 128];
                (&wv[ki].x)[u] = (lo & 0xffff) | (hi << 16);
            }
        }
    }

    __syncthreads();

    const int SH4  = 0x00040004;   // per-lane shift 4  (VGPR operand)
    const int SH15 = 0x000F000F;   // per-lane shift 15
    const int ONES = 0x00010001;   // two i16 ones for dot2
    int acc0 = 0, acc1 = 0, acc2 = 0, acc3 = 0;   // i32 (dot2-accumulated)

    #pragma unroll
    for (int row = 0; row < 3; ++row) {
        // 6 distinct x columns for this row (8 ch = one int4 each)
        const uint32_t* xb = xl + row * 256 + ce * 4;
        int4 xc[6];
        #pragma unroll
        for (int cidx = 0; cidx < 6; ++cidx)
            xc[cidx] = *(const int4*)(xb + cidx * 32);   // ds_read_b128 bcast
        #pragma unroll
        for (int j = 0; j < 3; ++j) {
            const int4 w4 = wv[row * 3 + j];
            #pragma unroll
            for (int u = 0; u < 4; ++u) {
                int w2 = (&w4.x)[u];
                int A  = pk_ashr(SH15, w2) & 0x000F000F;  // 15 per negative lane
                dot2_acc(acc0, pk_ashr(SH4, pk_mad_i16((&xc[j + 0].x)[u], w2, A)), ONES);
                dot2_acc(acc1, pk_ashr(SH4, pk_mad_i16((&xc[j + 1].x)[u], w2, A)), ONES);
                dot2_acc(acc2, pk_ashr(SH4, pk_mad_i16((&xc[j + 2].x)[u], w2, A)), ONES);
                dot2_acc(acc3, pk_ashr(SH4, pk_mad_i16((&xc[j + 3].x)[u], w2, A)), ONES);
            }
        }
    }

    // stash i32 partials
    prt[(ce * 4 + 0) * 64 + f64] = acc0;
    prt[(ce * 4 + 1) * 64 + f64] = acc1;
    prt[(ce * 4 + 2) * 64 + f64] = acc2;
    prt[(ce * 4 + 3) * 64 + f64] = acc3;
    __syncthreads();

    // reduce 8 c-eighths, bias, relu, store: 256 outputs, threads [0,256)
    if (tid < 256) {
        int ff = tid & 63;
        int px = tid >> 6;
        int v = 0;
        #pragma unroll
        for (int e = 0; e < 8; ++e) v += prt[(e * 4 + px) * 64 + ff];
        v += (int)bias[fh * 64 + ff];
        out[((b * 32 + h) * 32 + w0 + px) * 128 + fh * 64 + ff] =
            (float)(v < 0 ? 0 : v);
    }
}

extern "C" void kernel_launch(void* const* d_in, const int* in_sizes, int n_in,
                              void* d_out, int out_size, void* d_ws, size_t ws_size,
                              hipStream_t stream) {
    const float* input  = (const float*)d_in[0];   // [4,32,32,64]
    const float* kernel = (const float*)d_in[1];   // [3,3,64,128]
    const float* bias   = (const float*)d_in[2];   // [128]
    // d_in[3] = bits (==4, baked into the closed form)

    conv_fused<<<2048, 512, 0, stream>>>(input, kernel, bias, (float*)d_out);
}